// Round 3
// baseline (1871.485 us; speedup 1.0000x reference)
//
#include <hip/hip_runtime.h>

// Problem: B=4, C=64, H=W=256, 4x4 tiles of 64, dynamic 3x3 conv 64->32 per tile.
// Inputs f32 (proven: bf16 decode of inputs NaN-poisoned round 1).
// Output f32 (reference's output dtype per harness contract; round-2 error
// signature matched u16-into-f32-buffer recombination).
// h (conv1 output) is staged in f32 inside d_out planes (b*96 + c), c<64,
// then overwritten by the feature passthrough at the end of the launch.

// ---------------------------------------------------------------------------
// Generic 3x3 conv, 16 output channels per block, 2 pixels per thread.
// Block: 256 threads = 16x16, spatial tile 32(w) x 16(h).
// MODE 0: conv1  — in=feature, w=rw1, bias=rb1, leaky ReLU ->
//                  h planes in d_out at (b*96 + oc), oc<64
// MODE 1: dyncnv — in=feature, w/bias from wb (per-tile row) ->
//                  d_out planes (b*96 + 64 + oc), oc<32
// ---------------------------------------------------------------------------
template <int MODE>
__global__ __launch_bounds__(256) void conv3x3_k(
    const float* __restrict__ in,    // feature f32 [4][64][256][256]
    const float* __restrict__ wbf,   // MODE0: rw1 [64][64][3][3]
    const float* __restrict__ bbf,   // MODE0: rb1 [64]
    const float* __restrict__ wb,    // MODE1: wb [64][18464]
    float* __restrict__ outb)        // d_out f32 [4][96][256][256]
{
    __shared__ float sIn[16 * 18 * 35];  // 16 ic x 18 rows x (34 cols +1 pad)
    __shared__ float sW[16 * 9 * 16];    // [ic][k][oc] — oc contiguous

    const int bx = blockIdx.x, by = blockIdx.y, bz = blockIdx.z;
    int b, ocg;
    if (MODE == 0) { b = bz >> 2; ocg = bz & 3; }
    else           { b = bz >> 1; ocg = bz & 1; }
    const int tid = threadIdx.x;
    const int tx = tid & 15, ty = tid >> 4;
    const int x0 = bx * 32, y0 = by * 16;

    int bt = 0;
    const float* wsrc;
    if (MODE == 0) {
        wsrc = wbf + ocg * 16 * 576;
    } else {
        bt = b * 16 + (by >> 2) * 4 + (bx >> 1);   // tile index for this block
        wsrc = wb + (size_t)bt * 18464 + ocg * 16 * 576;
    }

    float acc0[16], acc1[16];
#pragma unroll
    for (int i = 0; i < 16; ++i) { acc0[i] = 0.f; acc1[i] = 0.f; }

    for (int cc = 0; cc < 4; ++cc) {  // 4 chunks of 16 input channels
        __syncthreads();
        // stage input halo tile: 16 ic x 18 x 34 (global zero-pad)
        for (int idx = tid; idx < 16 * 18 * 34; idx += 256) {
            int ic = idx / 612;
            int rem = idx - ic * 612;
            int row = rem / 34;
            int col = rem - row * 34;
            int gy = y0 + row - 1, gx = x0 + col - 1;
            float v = 0.f;
            if ((unsigned)gy < 256u && (unsigned)gx < 256u)
                v = in[(((size_t)b * 64 + cc * 16 + ic) * 256 + gy) * 256 + gx];
            sIn[ic * 630 + row * 35 + col] = v;
        }
        // stage weights transposed to [ic][k][oc]
        for (int idx = tid; idx < 2304; idx += 256) {
            int ic = idx / 144;
            int rem = idx - ic * 144;
            int k = rem >> 4;
            int oc = rem & 15;
            size_t gsrc = ((size_t)oc * 64 + cc * 16 + ic) * 9 + k;
            sW[idx] = wsrc[gsrc];
        }
        __syncthreads();

        for (int ic = 0; ic < 16; ++ic) {
            const float* sI = &sIn[ic * 630 + ty * 35 + tx];
            const float* sWi = &sW[ic * 144];
#pragma unroll
            for (int k = 0; k < 9; ++k) {
                const int kh = k / 3, kw = k - kh * 3;
                float i0 = sI[kh * 35 + kw];
                float i1 = sI[kh * 35 + kw + 16];
                float w[16];
                *(float4*)&w[0]  = *(const float4*)&sWi[k * 16 + 0];
                *(float4*)&w[4]  = *(const float4*)&sWi[k * 16 + 4];
                *(float4*)&w[8]  = *(const float4*)&sWi[k * 16 + 8];
                *(float4*)&w[12] = *(const float4*)&sWi[k * 16 + 12];
#pragma unroll
                for (int oc = 0; oc < 16; ++oc) {
                    acc0[oc] += i0 * w[oc];
                    acc1[oc] += i1 * w[oc];
                }
            }
        }
    }

    const int gy = y0 + ty;
#pragma unroll
    for (int oc = 0; oc < 16; ++oc) {
        if (MODE == 0) {
            float bv = bbf[ocg * 16 + oc];
            float v0 = acc0[oc] + bv, v1 = acc1[oc] + bv;
            v0 = (v0 >= 0.f) ? v0 : 0.2f * v0;   // leaky relu
            v1 = (v1 >= 0.f) ? v1 : 0.2f * v1;
            size_t o = (((size_t)b * 96 + ocg * 16 + oc) * 256 + gy) * 256 + x0 + tx;
            outb[o] = v0;
            outb[o + 16] = v1;
        } else {
            float bv = wb[(size_t)bt * 18464 + 18432 + ocg * 16 + oc];
            size_t o = (((size_t)b * 96 + 64 + ocg * 16 + oc) * 256 + gy) * 256 + x0 + tx;
            outb[o] = acc0[oc] + bv;
            outb[o + 16] = acc1[oc] + bv;
        }
    }
}

// ---------------------------------------------------------------------------
// conv2: 64 -> 1 channel, 3x3 pad 1, + bias + tanh. Reads f32 h from d_out
// planes (b*96 + ic).
// ---------------------------------------------------------------------------
__global__ __launch_bounds__(256) void conv2_tanh_k(
    const float* __restrict__ hin,   // d_out f32, h at planes b*96 + 0..63
    const float* __restrict__ rw2,   // [1][64][3][3]
    const float* __restrict__ rb2,   // [1]
    float* __restrict__ ad)          // adaptive f32 [4][256][256]
{
    __shared__ float sIn[16 * 18 * 35];
    __shared__ float sW[144];
    const int bx = blockIdx.x, by = blockIdx.y, b = blockIdx.z;
    const int tid = threadIdx.x;
    const int tx = tid & 15, ty = tid >> 4;
    const int x0 = bx * 32, y0 = by * 16;
    float a0 = 0.f, a1 = 0.f;

    for (int cc = 0; cc < 4; ++cc) {
        __syncthreads();
        for (int idx = tid; idx < 16 * 18 * 34; idx += 256) {
            int ic = idx / 612;
            int rem = idx - ic * 612;
            int row = rem / 34;
            int col = rem - row * 34;
            int gy = y0 + row - 1, gx = x0 + col - 1;
            float v = 0.f;
            if ((unsigned)gy < 256u && (unsigned)gx < 256u)
                v = hin[(((size_t)b * 96 + cc * 16 + ic) * 256 + gy) * 256 + gx];
            sIn[ic * 630 + row * 35 + col] = v;
        }
        if (tid < 144) sW[tid] = rw2[cc * 144 + tid];
        __syncthreads();

        for (int ic = 0; ic < 16; ++ic) {
            const float* sI = &sIn[ic * 630 + ty * 35 + tx];
            const float* sWi = &sW[ic * 9];
#pragma unroll
            for (int k = 0; k < 9; ++k) {
                const int kh = k / 3, kw = k - kh * 3;
                float w = sWi[k];
                a0 += sI[kh * 35 + kw] * w;
                a1 += sI[kh * 35 + kw + 16] * w;
            }
        }
    }
    float bias = rb2[0];
    size_t o = ((size_t)b * 256 + y0 + ty) * 256 + x0 + tx;
    ad[o] = tanhf(a0 + bias);
    ad[o + 16] = tanhf(a1 + bias);
}

// ---------------------------------------------------------------------------
// Adaptive-avg gram: per (bt, p, q) average the 66->32 window over the padded
// 66x66 tile of `adaptive`. Denominator counts pad zeros (matches reference).
// ---------------------------------------------------------------------------
__global__ __launch_bounds__(256) void gram_pool_k(
    const float* __restrict__ adaptive, float* __restrict__ gram)
{
    int idx = blockIdx.x * 256 + threadIdx.x;  // 64*1024
    int bt = idx >> 10;
    int pq = idx & 1023;
    int p = pq >> 5, q = pq & 31;
    int b = bt >> 4, t = bt & 15;
    int ti = t >> 2, tj = t & 3;
    int sp = (p * 33) >> 4, ep = ((p + 1) * 33 + 15) >> 4;  // 66/32 == 33/16
    int sq = (q * 33) >> 4, eq = ((q + 1) * 33 + 15) >> 4;
    float s = 0.f;
    for (int hh = sp; hh < ep; ++hh) {
        int gy = ti * 64 + hh - 1;
        if ((unsigned)gy >= 256u) continue;
        for (int w = sq; w < eq; ++w) {
            int gx = tj * 64 + w - 1;
            if ((unsigned)gx < 256u) s += adaptive[((size_t)b * 256 + gy) * 256 + gx];
        }
    }
    gram[idx] = s / (float)((ep - sp) * (eq - sq));
}

// ---------------------------------------------------------------------------
// FC: C[64,N] = act(A[64,K] @ B[K,N] + bias). All f32.
// Block computes a 64x64 tile of C; threads 16x16, 4x4 per thread.
// ---------------------------------------------------------------------------
__global__ __launch_bounds__(256) void fc_gemm_k(
    const float* __restrict__ A, const float* __restrict__ Bm,
    const float* __restrict__ bias, float* __restrict__ Cm,
    int K, int N, int act)
{
    __shared__ float As[16][68];  // [kk][m]
    __shared__ float Bs[16][64];  // [kk][n]
    const int n0 = blockIdx.x * 64;
    const int tid = threadIdx.x;
    const int tx = tid & 15, ty = tid >> 4;
    float acc[4][4];
#pragma unroll
    for (int i = 0; i < 4; ++i)
#pragma unroll
        for (int j = 0; j < 4; ++j) acc[i][j] = 0.f;

    const int mA = tid >> 2, kA = (tid & 3) * 4;
    const int kB = tid >> 4, nB = (tid & 15) * 4;

    for (int k0 = 0; k0 < K; k0 += 16) {
        __syncthreads();
        float4 av = *(const float4*)&A[(size_t)mA * K + k0 + kA];
        As[kA + 0][mA] = av.x;
        As[kA + 1][mA] = av.y;
        As[kA + 2][mA] = av.z;
        As[kA + 3][mA] = av.w;
        {
            int gn = n0 + nB;
            const float* bp = Bm + (size_t)(k0 + kB) * N + gn;
            float b0 = 0.f, b1 = 0.f, b2 = 0.f, b3 = 0.f;
            if (gn + 3 < N) {
                float4 u = *(const float4*)bp;
                b0 = u.x; b1 = u.y; b2 = u.z; b3 = u.w;
            } else {
                if (gn < N)     b0 = bp[0];
                if (gn + 1 < N) b1 = bp[1];
                if (gn + 2 < N) b2 = bp[2];
            }
            Bs[kB][nB + 0] = b0; Bs[kB][nB + 1] = b1;
            Bs[kB][nB + 2] = b2; Bs[kB][nB + 3] = b3;
        }
        __syncthreads();
#pragma unroll
        for (int kk = 0; kk < 16; ++kk) {
            float4 a = *(const float4*)&As[kk][ty * 4];
            float4 bb = *(const float4*)&Bs[kk][tx * 4];
            acc[0][0] += a.x * bb.x; acc[0][1] += a.x * bb.y; acc[0][2] += a.x * bb.z; acc[0][3] += a.x * bb.w;
            acc[1][0] += a.y * bb.x; acc[1][1] += a.y * bb.y; acc[1][2] += a.y * bb.z; acc[1][3] += a.y * bb.w;
            acc[2][0] += a.z * bb.x; acc[2][1] += a.z * bb.y; acc[2][2] += a.z * bb.z; acc[2][3] += a.z * bb.w;
            acc[3][0] += a.w * bb.x; acc[3][1] += a.w * bb.y; acc[3][2] += a.w * bb.z; acc[3][3] += a.w * bb.w;
        }
    }
#pragma unroll
    for (int i = 0; i < 4; ++i) {
        int m = ty * 4 + i;
#pragma unroll
        for (int j = 0; j < 4; ++j) {
            int n = n0 + tx * 4 + j;
            if (n < N) {
                float v = acc[i][j] + bias[n];
                if (act) v = fmaxf(v, 0.f);
                Cm[(size_t)m * N + n] = v;
            }
        }
    }
}

// ---------------------------------------------------------------------------
// feature (f32) -> f32 passthrough into output channels 0..63 (plane remap).
// Runs LAST: overwrites the h staging planes.
// ---------------------------------------------------------------------------
__global__ __launch_bounds__(256) void copy_feat_k(
    const float4* __restrict__ f, float4* __restrict__ o)
{
    int idx = blockIdx.x * 256 + threadIdx.x;  // 4,194,304 float4
    int plane = idx >> 14;                     // b*64 + c (16384 f4 / plane)
    int off = idx & 16383;
    int b = plane >> 6, c = plane & 63;
    o[((size_t)(b * 96 + c)) * 16384 + off] = f[idx];
}

extern "C" void kernel_launch(void* const* d_in, const int* in_sizes, int n_in,
                              void* d_out, int out_size, void* d_ws, size_t ws_size,
                              hipStream_t stream) {
    const float* feature = (const float*)d_in[0];
    const float* rw1 = (const float*)d_in[1];
    const float* rb1 = (const float*)d_in[2];
    const float* rw2 = (const float*)d_in[3];
    const float* rb2 = (const float*)d_in[4];
    const float* fw1 = (const float*)d_in[5];
    const float* fb1 = (const float*)d_in[6];
    const float* fw2 = (const float*)d_in[7];
    const float* fb2 = (const float*)d_in[8];
    const float* fw3 = (const float*)d_in[9];
    const float* fb3 = (const float*)d_in[10];
    float* out = (float*)d_out;

    // Workspace layout (~7.1 MB):
    float* adaptive = (float*)d_ws;                   // 262,144 f32
    float* gram = adaptive + 262144;                  // 65,536 f32
    float* g1 = gram + 65536;                         // 131,072 f32
    float* g2 = g1 + 131072;                          // 131,072 f32
    float* wb = g2 + 131072;                          // 1,181,696 f32

    // 1. conv1 + leaky relu -> h staged in d_out planes (b*96 + 0..63)
    conv3x3_k<0><<<dim3(8, 16, 16), 256, 0, stream>>>(feature, rw1, rb1, nullptr, out);
    // 2. conv2 + tanh -> adaptive (reads h from d_out)
    conv2_tanh_k<<<dim3(8, 16, 4), 256, 0, stream>>>(out, rw2, rb2, adaptive);
    // 3. adaptive-avg gram -> gram [64][1024]
    gram_pool_k<<<dim3(256), 256, 0, stream>>>(adaptive, gram);
    // 4-6. FC stack -> wb [64][18464]
    fc_gemm_k<<<dim3(32), 256, 0, stream>>>(gram, fw1, fb1, g1, 1024, 2048, 1);
    fc_gemm_k<<<dim3(32), 256, 0, stream>>>(g1, fw2, fb2, g2, 2048, 2048, 1);
    fc_gemm_k<<<dim3(289), 256, 0, stream>>>(g2, fw3, fb3, wb, 2048, 18464, 0);
    // 7. dynamic per-tile conv -> out channels 64..95 (+ bias, spliced)
    conv3x3_k<1><<<dim3(8, 16, 8), 256, 0, stream>>>(feature, nullptr, nullptr, wb, out);
    // 8. passthrough: feature -> out channels 0..63 (overwrites h staging)
    copy_feat_k<<<dim3(16384), 256, 0, stream>>>((const float4*)feature, (float4*)out);
}